// Round 3
// baseline (233.895 us; speedup 1.0000x reference)
//
#include <hip/hip_runtime.h>

// ---------------- problem constants (fixed by setup_inputs) ----------------
constexpr int B_ = 2, N_ = 8192, M_ = 8192, Dd = 64;
constexpr int TN = 128;              // n-rows per block (4 waves x 32)
constexpr int TM = 64;               // ref rows per chunk (small -> 4 blocks/CU)
constexpr int SPLIT = 8;             // M-splits; blockIdx&7 pins split->XCD
constexpr int MCHUNK = M_ / SPLIT;   // 1024
constexpr int NCHUNKS = MCHUNK / TM; // 16
constexpr int NT = N_ / TN;          // 64
constexpr float LOG2E   = 1.4426950408889634f;
constexpr float SCALE_S = LOG2E / 64.0f;    //  dot/64    in log2 domain
constexpr float SCALE_N = -LOG2E / 128.0f;  // -|v|^2/128 in log2 domain

using s16x8 = __attribute__((ext_vector_type(8))) short;
using f32x4 = __attribute__((ext_vector_type(4))) float;

#if defined(__has_builtin)
#if __has_builtin(__builtin_amdgcn_exp2f)
#define EXP2(x) __builtin_amdgcn_exp2f(x)
#endif
#endif
#ifndef EXP2
#define EXP2(x) exp2f(x)
#endif

__device__ __forceinline__ unsigned short f2bf(float f) {
  unsigned u = __builtin_bit_cast(unsigned, f);
  u += 0x7FFFu + ((u >> 16) & 1u);   // RNE (values finite)
  return (unsigned short)(u >> 16);
}
__device__ __forceinline__ unsigned pk2(float lo, float hi) {
  return (unsigned)f2bf(lo) | ((unsigned)f2bf(hi) << 16);
}
__device__ __forceinline__ f32x4 mfma16(s16x8 a, s16x8 b, f32x4 c) {
  return __builtin_amdgcn_mfma_f32_16x16x32_bf16(a, b, c, 0, 0, 0);
}

// Frag layouts (m89/m91): A/B: outer=lane&15 (A:row, B:col), 8 k-contig at (lane>>4)*8.
// C/D: col = lane&15, row = (lane>>4)*4 + reg.
// This kernel computes S^T = Y*X^T and O^T = Y^T*P^T so that C/D reg groups are
// m-contiguous (vector b64 P-writes) and P re-enters as a B-operand (vector b128 reads).

__global__ __launch_bounds__(256, 4) void msflash_kernel(
    const float* __restrict__ pts, const float* __restrict__ ref,
    float* __restrict__ num_acc, float* __restrict__ den_acc) {
  // strides: 72 shorts = 144 B = 16B*9 -> b128-aligned, non-pow2 (bank-spread)
  __shared__ unsigned short ldsY [TM][72];    // Y chunk [m][d]  (QK A-frags)   9216 B
  __shared__ unsigned short ldsYT[Dd][72];    // Y chunk [d][m]  (PV A-frags)   9216 B
  __shared__ unsigned short ldsP [4][32][72]; // per-wave P^T-ish [n][m]       18432 B
  __shared__ float lds_an2[TN];
  __shared__ float lds_bm2[TM];
  // total 37,632 B -> 4 blocks/CU

  const int tid  = threadIdx.x;
  const int w    = tid >> 6;
  const int lane = tid & 63;
  const int l15  = lane & 15, quad = lane >> 4;

  const int s  = blockIdx.x & (SPLIT - 1);
  const int r  = blockIdx.x >> 3;
  const int bb = r / NT;
  const int nt = r % NT;
  const int n0 = nt * TN;
  const int m_begin = s * MCHUNK;

  // ---- stage X (fp32 -> bf16) into ldsP alias (wave-private rows) + row norms ----
  unsigned short (*ldsX)[72] = (unsigned short (*)[72]) & ldsP[0][0][0]; // 128x72 alias
  {
    const int rowl = tid >> 1, half = tid & 1;
    const float* gp = pts + ((size_t)bb * N_ + n0 + rowl) * Dd + half * 32;
    float sq = 0.f;
    unsigned pkd[16];
#pragma unroll
    for (int i = 0; i < 8; i++) {
      float4 f = ((const float4*)gp)[i];
      sq += f.x * f.x + f.y * f.y + f.z * f.z + f.w * f.w;
      pkd[2 * i + 0] = pk2(f.x, f.y);
      pkd[2 * i + 1] = pk2(f.z, f.w);
    }
    sq += __shfl_xor(sq, 1);
    if (half == 0) lds_an2[rowl] = sq * SCALE_N;
    uint4* dv = (uint4*)&ldsX[rowl][half * 32];
#pragma unroll
    for (int i = 0; i < 4; i++)
      dv[i] = make_uint4(pkd[4 * i], pkd[4 * i + 1], pkd[4 * i + 2], pkd[4 * i + 3]);
  }
  __syncthreads();

  // X B-frags (col = n) + per-row -|x|^2 term; wave reads ONLY its own ldsP region
  s16x8 bx[2][2];
  float anr_s[2];
#pragma unroll
  for (int rt = 0; rt < 2; rt++) {
#pragma unroll
    for (int ks = 0; ks < 2; ks++)
      bx[rt][ks] = *(const s16x8*)&ldsX[w * 32 + rt * 16 + l15][ks * 32 + quad * 8];
    anr_s[rt] = lds_an2[w * 32 + rt * 16 + l15];
  }

  f32x4 o[2][4], den[2];
#pragma unroll
  for (int rt = 0; rt < 2; rt++) {
    den[rt] = f32x4{0.f, 0.f, 0.f, 0.f};
#pragma unroll
    for (int dt = 0; dt < 4; dt++) o[rt][dt] = f32x4{0.f, 0.f, 0.f, 0.f};
  }
  s16x8 ones;  // A-operand: row 0 all-ones -> D row 0 = column sums of B
#pragma unroll
  for (int j = 0; j < 8; j++) ones[j] = (l15 == 0) ? (short)0x3F80 : (short)0;

  for (int c = 0; c < NCHUNKS; c++) {
    __syncthreads();  // previous chunk's reads of ldsY/ldsYT done
    {   // ---- stage Y chunk: [m][d], transpose [d][m], and -|y|^2/128 terms ----
      const int rowl = tid >> 2, q = tid & 3;
      const float* gp = ref + ((size_t)bb * M_ + m_begin + c * TM + rowl) * Dd + q * 16;
      float sq = 0.f;
      unsigned pkd[8];
#pragma unroll
      for (int i = 0; i < 4; i++) {
        float4 f = ((const float4*)gp)[i];
        sq += f.x * f.x + f.y * f.y + f.z * f.z + f.w * f.w;
        pkd[2 * i + 0] = pk2(f.x, f.y);
        pkd[2 * i + 1] = pk2(f.z, f.w);
      }
      sq += __shfl_xor(sq, 1);
      sq += __shfl_xor(sq, 2);
      if (q == 0) lds_bm2[rowl] = sq * SCALE_N;
      uint4* dv = (uint4*)&ldsY[rowl][q * 16];
      dv[0] = make_uint4(pkd[0], pkd[1], pkd[2], pkd[3]);
      dv[1] = make_uint4(pkd[4], pkd[5], pkd[6], pkd[7]);
#pragma unroll
      for (int j = 0; j < 8; j++) {
        ldsYT[q * 16 + 2 * j + 0][rowl] = (unsigned short)pkd[j];
        ldsYT[q * 16 + 2 * j + 1][rowl] = (unsigned short)(pkd[j] >> 16);
      }
    }
    __syncthreads();

    // ---- QK: S^T tiles (16m x 16n), A = Y[m][d], B = X[n][d] ----
    f32x4 sf[2][4];
#pragma unroll
    for (int ct = 0; ct < 4; ct++) {
      s16x8 a0 = *(const s16x8*)&ldsY[ct * 16 + l15][quad * 8];
      s16x8 a1 = *(const s16x8*)&ldsY[ct * 16 + l15][32 + quad * 8];
#pragma unroll
      for (int rt = 0; rt < 2; rt++) {
        f32x4 acc = f32x4{0.f, 0.f, 0.f, 0.f};
        acc = mfma16(a0, bx[rt][0], acc);
        acc = mfma16(a1, bx[rt][1], acc);
        sf[rt][ct] = acc;
      }
    }
    // ---- exp2 + vector b64 P write: ldsP[w][n][m], lane's 4 values m-contig ----
#pragma unroll
    for (int ct = 0; ct < 4; ct++) {
      f32x4 bm = *(const f32x4*)&lds_bm2[ct * 16 + quad * 4];
#pragma unroll
      for (int rt = 0; rt < 2; rt++) {
        float e0 = EXP2(sf[rt][ct][0] * SCALE_S + (anr_s[rt] + bm[0]));
        float e1 = EXP2(sf[rt][ct][1] * SCALE_S + (anr_s[rt] + bm[1]));
        float e2 = EXP2(sf[rt][ct][2] * SCALE_S + (anr_s[rt] + bm[2]));
        float e3 = EXP2(sf[rt][ct][3] * SCALE_S + (anr_s[rt] + bm[3]));
        uint2 w2 = make_uint2(pk2(e0, e1), pk2(e2, e3));
        *(uint2*)&ldsP[w][rt * 16 + l15][ct * 16 + quad * 4] = w2;
      }
    }
    // ---- PV: O^T += Y^T * P^T, den += 1 * P^T (wave-private P, vector reads) ----
    s16x8 pf[2][2];
#pragma unroll
    for (int rt = 0; rt < 2; rt++)
#pragma unroll
      for (int ks = 0; ks < 2; ks++)
        pf[rt][ks] = *(const s16x8*)&ldsP[w][rt * 16 + l15][ks * 32 + quad * 8];
#pragma unroll
    for (int dt = 0; dt < 4; dt++) {
      s16x8 a0 = *(const s16x8*)&ldsYT[dt * 16 + l15][quad * 8];
      s16x8 a1 = *(const s16x8*)&ldsYT[dt * 16 + l15][32 + quad * 8];
#pragma unroll
      for (int rt = 0; rt < 2; rt++) {
        o[rt][dt] = mfma16(a0, pf[rt][0], o[rt][dt]);
        o[rt][dt] = mfma16(a1, pf[rt][1], o[rt][dt]);
      }
    }
#pragma unroll
    for (int rt = 0; rt < 2; rt++) {
      den[rt] = mfma16(ones, pf[rt][0], den[rt]);
      den[rt] = mfma16(ones, pf[rt][1], den[rt]);
    }
  }

  // ---- epilogue: O^T layout -> col=n (l15), row=d (quad*4+g); fp32 atomics ----
  float* nb = num_acc + ((size_t)bb * N_ + n0) * Dd;
#pragma unroll
  for (int rt = 0; rt < 2; rt++) {
    const int nrow = w * 32 + rt * 16 + l15;
#pragma unroll
    for (int dt = 0; dt < 4; dt++) {
      const int d0 = dt * 16 + quad * 4;
#pragma unroll
      for (int g = 0; g < 4; g++)
        atomicAdd(&nb[(size_t)nrow * Dd + d0 + g], o[rt][dt][g]);
    }
    if (quad == 0)  // den row 0 lives in reg 0 of quad 0
      atomicAdd(&den_acc[(size_t)bb * N_ + n0 + nrow], den[rt][0]);
  }
}

__global__ __launch_bounds__(256) void msdiv_kernel(
    const float* __restrict__ num, const float* __restrict__ den,
    float* __restrict__ out) {
  const int i = blockIdx.x * 256 + threadIdx.x;  // float4 index; grid covers exactly
  float4 v = ((const float4*)num)[i];
  const float inv = 1.0f / den[i >> 4];          // 16 float4 per 64-wide row
  ((float4*)out)[i] = make_float4(v.x * inv, v.y * inv, v.z * inv, v.w * inv);
}

extern "C" void kernel_launch(void* const* d_in, const int* in_sizes, int n_in,
                              void* d_out, int out_size, void* d_ws, size_t ws_size,
                              hipStream_t stream) {
  const float* pts = (const float*)d_in[0];
  const float* ref = (const float*)d_in[1];
  float* out = (float*)d_out;
  float* num = (float*)d_ws;                       // [B,N,64] fp32 partial numerators
  float* den = num + (size_t)B_ * N_ * Dd;         // [B,N]    fp32 partial denominators
  const size_t acc_bytes = ((size_t)B_ * N_ * Dd + (size_t)B_ * N_) * sizeof(float);

  hipMemsetAsync(d_ws, 0, acc_bytes, stream);      // ws is re-poisoned 0xAA each launch
  msflash_kernel<<<dim3(B_ * NT * SPLIT), dim3(256), 0, stream>>>(pts, ref, num, den);
  const int tot4 = B_ * N_ * Dd / 4;               // 262144
  msdiv_kernel<<<dim3(tot4 / 256), dim3(256), 0, stream>>>(num, den, out);
}

// Round 5
// 138.411 us; speedup vs baseline: 1.6899x; 1.6899x over previous
//
#include <hip/hip_runtime.h>

// ---------------- problem constants (fixed by setup_inputs) ----------------
constexpr int B_ = 2, N_ = 8192, M_ = 8192, Dd = 64;
constexpr int TN = 128;              // n-rows per block (4 waves x 32)
constexpr int TM = 64;               // ref rows per chunk (small -> 4 blocks/CU)
constexpr int SPLIT = 8;             // M-splits; blockIdx&7 pins split->XCD
constexpr int MCHUNK = M_ / SPLIT;   // 1024
constexpr int NCHUNKS = MCHUNK / TM; // 16
constexpr int NT = N_ / TN;          // 64
constexpr float LOG2E   = 1.4426950408889634f;
constexpr float SCALE_S = LOG2E / 64.0f;    //  dot/64    in log2 domain
constexpr float SCALE_N = -LOG2E / 128.0f;  // -|v|^2/128 in log2 domain

using s16x8 = __attribute__((ext_vector_type(8))) short;
using f32x4 = __attribute__((ext_vector_type(4))) float;

#if defined(__has_builtin)
#if __has_builtin(__builtin_amdgcn_exp2f)
#define EXP2(x) __builtin_amdgcn_exp2f(x)
#endif
#endif
#ifndef EXP2
#define EXP2(x) exp2f(x)
#endif

__device__ __forceinline__ unsigned short f2bf(float f) {
  unsigned u = __builtin_bit_cast(unsigned, f);
  u += 0x7FFFu + ((u >> 16) & 1u);   // RNE (values finite)
  return (unsigned short)(u >> 16);
}
__device__ __forceinline__ unsigned pk2(float lo, float hi) {
  return (unsigned)f2bf(lo) | ((unsigned)f2bf(hi) << 16);
}
__device__ __forceinline__ f32x4 mfma16(s16x8 a, s16x8 b, f32x4 c) {
  return __builtin_amdgcn_mfma_f32_16x16x32_bf16(a, b, c, 0, 0, 0);
}

// Frag layouts (m89/m91): A/B: outer=lane&15 (A:row i, B:col j), 8 k-contig at (lane>>4)*8.
// C/D: col = lane&15, row = (lane>>4)*4 + reg.
// Computes S^T = Y*X^T and O^T = Y^T*P^T (C/D reg groups m-/d-contiguous -> vector LDS ops).

__global__ __launch_bounds__(256, 4) void msflash_kernel(
    const float* __restrict__ pts, const float* __restrict__ ref,
    float* __restrict__ num_acc, float* __restrict__ den_acc) {
  // strides: 72 shorts = 144 B = 16B*9 -> b128-aligned, non-pow2 (bank-spread)
  __shared__ unsigned short ldsY [TM][72];    // Y chunk [m][d]  (QK A-frags)   9216 B
  __shared__ unsigned short ldsYT[Dd][72];    // Y chunk [d][m]  (PV A-frags)   9216 B
  __shared__ unsigned short ldsP [4][32][72]; // per-wave P [n][m] / X-stage / O-scratch
  __shared__ float lds_an2[TN];
  __shared__ float lds_bm2[TM];
  // total 37,632 B -> 4 blocks/CU

  const int tid  = threadIdx.x;
  const int w    = tid >> 6;
  const int lane = tid & 63;
  const int l15  = lane & 15, quad = lane >> 4;

  const int s  = blockIdx.x & (SPLIT - 1);
  const int r  = blockIdx.x >> 3;
  const int bb = r / NT;
  const int nt = r % NT;
  const int n0 = nt * TN;
  const int m_begin = s * MCHUNK;

  // ---- stage X (fp32 -> bf16) into ldsP alias (wave-private rows) + row norms ----
  unsigned short (*ldsX)[72] = (unsigned short (*)[72]) & ldsP[0][0][0]; // 128x72 alias
  {
    const int rowl = tid >> 1, half = tid & 1;
    const float* gp = pts + ((size_t)bb * N_ + n0 + rowl) * Dd + half * 32;
    float sq = 0.f;
    unsigned pkd[16];
#pragma unroll
    for (int i = 0; i < 8; i++) {
      float4 f = ((const float4*)gp)[i];
      sq += f.x * f.x + f.y * f.y + f.z * f.z + f.w * f.w;
      pkd[2 * i + 0] = pk2(f.x, f.y);
      pkd[2 * i + 1] = pk2(f.z, f.w);
    }
    sq += __shfl_xor(sq, 1);
    if (half == 0) lds_an2[rowl] = sq * SCALE_N;
    uint4* dv = (uint4*)&ldsX[rowl][half * 32];
#pragma unroll
    for (int i = 0; i < 4; i++)
      dv[i] = make_uint4(pkd[4 * i], pkd[4 * i + 1], pkd[4 * i + 2], pkd[4 * i + 3]);
  }
  __syncthreads();

  // X B-frags (col = n) + per-row -|x|^2 term (all wave-private reads)
  s16x8 bx[2][2];
  float anr_s[2];
#pragma unroll
  for (int rt = 0; rt < 2; rt++) {
#pragma unroll
    for (int ks = 0; ks < 2; ks++)
      bx[rt][ks] = *(const s16x8*)&ldsX[w * 32 + rt * 16 + l15][ks * 32 + quad * 8];
    anr_s[rt] = lds_an2[w * 32 + rt * 16 + l15];
  }

  f32x4 o[2][4], den[2];
#pragma unroll
  for (int rt = 0; rt < 2; rt++) {
    den[rt] = f32x4{0.f, 0.f, 0.f, 0.f};
#pragma unroll
    for (int dt = 0; dt < 4; dt++) o[rt][dt] = f32x4{0.f, 0.f, 0.f, 0.f};
  }
  s16x8 ones;  // A row 0 all-ones -> D row 0 = column sums of B
#pragma unroll
  for (int j = 0; j < 8; j++) ones[j] = (l15 == 0) ? (short)0x3F80 : (short)0;

  for (int c = 0; c < NCHUNKS; c++) {
    __syncthreads();  // previous chunk's reads of ldsY/ldsYT done
    {   // ---- stage Y chunk: [m][d], transpose [d][m], and -|y|^2/128 terms ----
      const int rowl = tid >> 2, q = tid & 3;
      const float* gp = ref + ((size_t)bb * M_ + m_begin + c * TM + rowl) * Dd + q * 16;
      float sq = 0.f;
      unsigned pkd[8];
#pragma unroll
      for (int i = 0; i < 4; i++) {
        float4 f = ((const float4*)gp)[i];
        sq += f.x * f.x + f.y * f.y + f.z * f.z + f.w * f.w;
        pkd[2 * i + 0] = pk2(f.x, f.y);
        pkd[2 * i + 1] = pk2(f.z, f.w);
      }
      sq += __shfl_xor(sq, 1);
      sq += __shfl_xor(sq, 2);
      if (q == 0) lds_bm2[rowl] = sq * SCALE_N;
      uint4* dv = (uint4*)&ldsY[rowl][q * 16];
      dv[0] = make_uint4(pkd[0], pkd[1], pkd[2], pkd[3]);
      dv[1] = make_uint4(pkd[4], pkd[5], pkd[6], pkd[7]);
#pragma unroll
      for (int j = 0; j < 8; j++) {
        ldsYT[q * 16 + 2 * j + 0][rowl] = (unsigned short)pkd[j];
        ldsYT[q * 16 + 2 * j + 1][rowl] = (unsigned short)(pkd[j] >> 16);
      }
    }
    __syncthreads();

    // ---- QK: S^T tiles (16m x 16n), A = Y[m][d], B = X[n][d] ----
    f32x4 sf[2][4];
#pragma unroll
    for (int ct = 0; ct < 4; ct++) {
      s16x8 a0 = *(const s16x8*)&ldsY[ct * 16 + l15][quad * 8];
      s16x8 a1 = *(const s16x8*)&ldsY[ct * 16 + l15][32 + quad * 8];
#pragma unroll
      for (int rt = 0; rt < 2; rt++) {
        f32x4 acc = f32x4{0.f, 0.f, 0.f, 0.f};
        acc = mfma16(a0, bx[rt][0], acc);
        acc = mfma16(a1, bx[rt][1], acc);
        sf[rt][ct] = acc;
      }
    }
    // ---- exp2 + vector b64 P write: ldsP[w][n][m], lane's 4 values m-contig ----
#pragma unroll
    for (int ct = 0; ct < 4; ct++) {
      f32x4 bm = *(const f32x4*)&lds_bm2[ct * 16 + quad * 4];
#pragma unroll
      for (int rt = 0; rt < 2; rt++) {
        float e0 = EXP2(sf[rt][ct][0] * SCALE_S + (anr_s[rt] + bm[0]));
        float e1 = EXP2(sf[rt][ct][1] * SCALE_S + (anr_s[rt] + bm[1]));
        float e2 = EXP2(sf[rt][ct][2] * SCALE_S + (anr_s[rt] + bm[2]));
        float e3 = EXP2(sf[rt][ct][3] * SCALE_S + (anr_s[rt] + bm[3]));
        uint2 w2 = make_uint2(pk2(e0, e1), pk2(e2, e3));
        *(uint2*)&ldsP[w][rt * 16 + l15][ct * 16 + quad * 4] = w2;
      }
    }
    // ---- PV: O^T += Y^T * P^T, den += 1 * P^T (wave-private P, vector reads) ----
    s16x8 pf[2][2];
#pragma unroll
    for (int rt = 0; rt < 2; rt++)
#pragma unroll
      for (int ks = 0; ks < 2; ks++)
        pf[rt][ks] = *(const s16x8*)&ldsP[w][rt * 16 + l15][ks * 32 + quad * 8];
#pragma unroll
    for (int dt = 0; dt < 4; dt++) {
      s16x8 a0 = *(const s16x8*)&ldsYT[dt * 16 + l15][quad * 8];
      s16x8 a1 = *(const s16x8*)&ldsYT[dt * 16 + l15][32 + quad * 8];
#pragma unroll
      for (int rt = 0; rt < 2; rt++) {
        o[rt][dt] = mfma16(a0, pf[rt][0], o[rt][dt]);
        o[rt][dt] = mfma16(a1, pf[rt][1], o[rt][dt]);
      }
    }
#pragma unroll
    for (int rt = 0; rt < 2; rt++) {
      den[rt] = mfma16(ones, pf[rt][0], den[rt]);
      den[rt] = mfma16(ones, pf[rt][1], den[rt]);
    }
  }

  // ---- epilogue: transpose O^T through wave-private LDS scratch, coalesced atomics ----
  // o[rt][dt][g] = O[n = w*32+rt*16+l15][d = dt*16+quad*4+g]  (C-layout: col=l15, row=quad*4+g)
  float* ldsO = (float*)&ldsP[w][0][0];  // wave-private 4608 B; use 16 rows x 66 floats (4224 B)
  float* nb = num_acc + ((size_t)bb * N_ + n0) * Dd;
#pragma unroll
  for (int rt = 0; rt < 2; rt++) {
#pragma unroll
    for (int dt = 0; dt < 4; dt++) {
      const int base = l15 * 66 + dt * 16 + quad * 4;
      *(float2*)&ldsO[base + 0] = make_float2(o[rt][dt][0], o[rt][dt][1]);
      *(float2*)&ldsO[base + 2] = make_float2(o[rt][dt][2], o[rt][dt][3]);
    }
    const int nrow = w * 32 + rt * 16;  // wave-private region: in-order LDS, no barrier
#pragma unroll
    for (int rr = 0; rr < 16; rr++) {
      float v = ldsO[rr * 66 + lane];
      atomicAdd(&nb[(size_t)(nrow + rr) * Dd + lane], v);  // 256B contiguous per instr
    }
    if (quad == 0)
      atomicAdd(&den_acc[(size_t)bb * N_ + n0 + nrow + l15], den[rt][0]);
  }
}

__global__ __launch_bounds__(256) void msdiv_kernel(
    const float* __restrict__ num, const float* __restrict__ den,
    float* __restrict__ out) {
  const int i = blockIdx.x * 256 + threadIdx.x;  // float4 index; grid covers exactly
  float4 v = ((const float4*)num)[i];
  const float inv = 1.0f / den[i >> 4];          // 16 float4 per 64-wide row
  ((float4*)out)[i] = make_float4(v.x * inv, v.y * inv, v.z * inv, v.w * inv);
}

extern "C" void kernel_launch(void* const* d_in, const int* in_sizes, int n_in,
                              void* d_out, int out_size, void* d_ws, size_t ws_size,
                              hipStream_t stream) {
  const float* pts = (const float*)d_in[0];
  const float* ref = (const float*)d_in[1];
  float* out = (float*)d_out;
  float* num = (float*)d_ws;                       // [B,N,64] fp32 partial numerators
  float* den = num + (size_t)B_ * N_ * Dd;         // [B,N]    fp32 partial denominators
  const size_t acc_bytes = ((size_t)B_ * N_ * Dd + (size_t)B_ * N_) * sizeof(float);

  hipMemsetAsync(d_ws, 0, acc_bytes, stream);      // ws is re-poisoned 0xAA each launch
  msflash_kernel<<<dim3(B_ * NT * SPLIT), dim3(256), 0, stream>>>(pts, ref, num, den);
  const int tot4 = B_ * N_ * Dd / 4;               // 262144
  msdiv_kernel<<<dim3(tot4 / 256), dim3(256), 0, stream>>>(num, den, out);
}